// Round 2
// 337.144 us; speedup vs baseline: 1.0916x; 1.0916x over previous
//
#include <hip/hip_runtime.h>

// ============================================================================
// TypeNet triplet embedder: 2x(LSTM + BatchNorm) + FC + L2norm, for a,p,n.
// Round 8 (resubmit — R1 bench was GPUAcquisitionTimeout, no data):
//  - exp2 folding: gate pre-activations pre-scaled by -log2e (-2log2e for g)
//    inside the folded weights/biases, so the cell uses raw v_exp_f32 with
//    no argument multiplies. 5 exp2 + 2 rcp per cell (merged f/ig denom).
//  - Step reorder: BAR -> ds_read A-frags -> x-part MFMA (no LDS dep) ->
//    h-part MFMA -> cell. LDS read latency hides under x-part MFMAs.
//  - h_last hoisted out of the lstm2 loop; BN sums deferred past LDS writes.
//  - Weights stored in B-frag order (prep/mid) -> prologue loads are 16B
//    coalesced half8 instead of 256 scalar 2B loads per thread.
//  - prep_all vectorized (half8 writes, 834 blocks); mid bias loop LDS-staged.
// ============================================================================

typedef __attribute__((ext_vector_type(8))) _Float16 half8;
typedef __attribute__((ext_vector_type(4))) float f32x4;

#define TS 128
#define HID 128
#define NGATE 512
#define INV_N (1.0f/65536.0f)   // 1/(B*T)
#define NL2E  -1.4426950408889634f   // -log2(e)
#define N2L2E -2.8853900817779268f   // -2*log2(e)
#define GCLAMP 57.707801635558536f   // 20 * 2*log2(e)

#define BAR() asm volatile("s_waitcnt lgkmcnt(0)\n\ts_barrier" ::: "memory")

__device__ __forceinline__ float rcpf(float x) { return __builtin_amdgcn_rcpf(x); }
__device__ __forceinline__ float ex2(float x) { return __builtin_amdgcn_exp2f(x); }

// Gate pre-activations arrive PRE-SCALED: zi,zf,zo = -log2e*z, zg = -2log2e*z.
// sigmoid(i)*tanh(g) and sigmoid(f) share one reciprocal.
// 5 exp2 + 2 rcp + ~17 VALU per cell.
__device__ __forceinline__ float lstm_cell(float zi, float zf, float zg, float zo,
                                           float& c) {
  float zgc = __builtin_amdgcn_fmed3f(zg, -GCLAMP, GCLAMP);
  float ei = ex2(zi);
  float ef = ex2(zf);
  float eg = ex2(zgc);
  float eo = ex2(zo);
  float pi = 1.0f + ei, pg = 1.0f + eg, pf = 1.0f + ef;
  float P = pi * pg;
  float rd = rcpf(P * pf);
  float fv = P * rd;                    // sigmoid(zf)
  float ig = (1.0f - eg) * (pf * rd);   // sigmoid(zi)*tanh(zg)
  float cc = fv * c + ig;
  c = cc;
  float t2 = __builtin_amdgcn_fmed3f(cc * N2L2E, -GCLAMP, GCLAMP);
  float ec = ex2(t2);
  float hv = (1.0f - ec) * rcpf((1.0f + eo) * (1.0f + ec));  // sigmoid(zo)*tanh(cc)
  return hv;
}

// A-frag LDS/global layout for a 16x128 fp16 tile:
//   addr(row, col) = (col>>5)*512 + ((col>>3)&3)*128 + row*8 + (col&7)
// Reader (MFMA A-frag, row=l15, k=kt*32+quad*8+j): base = kt*512+(quad*16+l15)*8
// => lane-contiguous 16B blocks, conflict-free ds_read_b128.
//
// Weight (B-frag) layout: group index kq = kt*4+quad; element
//   w[kq*512 + g][j] = W^T[kt*32+quad*8+j][g]  (gate-scaled by -log2e/-2log2e)
// => per-thread half8 at &w[(kq*512 + g)*8], 16B coalesced.

// ---------------------------------------------------------------------------
// Fused prep: xpad (A-frag fp16 x), B-frag scaled WhhT both layers, bias1.
// ---------------------------------------------------------------------------
__global__ void prep_all(const float* __restrict__ xa, const float* __restrict__ xp,
                         const float* __restrict__ xn,
                         const float* __restrict__ Whh1, const float* __restrict__ Whh2,
                         const float* __restrict__ bih1, const float* __restrict__ bhh1,
                         _Float16* __restrict__ xpad,
                         _Float16* __restrict__ whhT1, _Float16* __restrict__ whhT2,
                         float* __restrict__ b1c) {
  int bid = blockIdx.x, tid = threadIdx.x;
  if (bid < 768) {                       // xpad: one half8 per (tile,t,r)
    int i = bid * 256 + tid;             // [0, 196608)
    int tile = i >> 11, rem = i & 2047;
    int t = rem >> 4, r = rem & 15;
    int inp = tile >> 5, rloc = (tile & 31) * 16;
    const float* x = (inp == 0) ? xa : ((inp == 1) ? xp : xn);
    const float* row = x + (size_t)(rloc + r) * 640 + t * 5;
    half8 v = {0, 0, 0, 0, 0, 0, 0, 0};
#pragma unroll
    for (int j = 0; j < 5; ++j) v[j] = (_Float16)row[j];
    *(half8*)&xpad[(size_t)i * 8] = v;
  } else if (bid < 832) {                // whhT1/2: B-frag order, gate-scaled
    int i = (bid - 768) * 256 + tid;     // [0, 16384)
    int which = i >> 13, i8 = i & 8191;
    int kq = i8 >> 9, g = i8 & 511;
    int k0 = (kq >> 2) * 32 + (kq & 3) * 8;
    float gs = ((g >> 7) == 2) ? N2L2E : NL2E;
    const float* src = which ? Whh2 : Whh1;
    half8 v;
#pragma unroll
    for (int j = 0; j < 8; ++j) v[j] = (_Float16)(src[(size_t)g * HID + k0 + j] * gs);
    *(half8*)&(which ? whhT2 : whhT1)[(size_t)i8 * 8] = v;
  } else {                               // b1c (gate-scaled combined bias)
    int i = (bid - 832) * 256 + tid;     // [0, 512)
    float gs = ((i >> 7) == 2) ? N2L2E : NL2E;
    b1c[i] = (bih1[i] + bhh1[i]) * gs;
  }
}

// ---------------------------------------------------------------------------
// LSTM layer 1. 96 WGs x 512. hs1: [96 tile][128 t][2048 halves] A-frag order.
// ---------------------------------------------------------------------------
__global__ __launch_bounds__(512, 2) void lstm1_kernel(
    const _Float16* __restrict__ xpad,   // [96][128][16][8]
    const float* __restrict__ Wih1,      // [512][5]
    const float* __restrict__ b1c,       // [512] scaled
    const _Float16* __restrict__ whhT,   // [16 kq][512 g][8] B-frag, scaled
    _Float16* __restrict__ hs1,
    float* __restrict__ s1sum, float* __restrict__ s1sq) {
  const int wg = blockIdx.x;             // tile 0..95
  const int inp = wg >> 5;
  const int tid = threadIdx.x;
  const int w = tid >> 6;                // 0..7
  const int lane = tid & 63;
  const int l15 = lane & 15;
  const int quad = lane >> 4;
  const int col = w * 16 + l15;

  __shared__ _Float16 hb[2][2048];       // double-buffered h, A-frag order, 8 KB
  for (int i = tid; i < 4096; i += 512) ((_Float16*)hb)[i] = (_Float16)0.0f;

  const int rbase = (quad * 16 + l15) * 8;
  const int wbase = (w >> 1) * 512 + ((w & 1) * 2 + (l15 >> 3)) * 128 +
                    quad * 32 + (l15 & 7);

  half8 bh[4][4];                        // [kt][gate], coalesced half8 loads
#pragma unroll
  for (int kt = 0; kt < 4; ++kt)
#pragma unroll
    for (int gt = 0; gt < 4; ++gt)
      bh[kt][gt] = *(const half8*)&whhT[(size_t)((kt * 4 + quad) * 512 + gt * 128 + col) * 8];

  half8 bx[4];                           // Wih1, gate-scaled, K=32-padded
#pragma unroll
  for (int gt = 0; gt < 4; ++gt) {
    half8 v = {0, 0, 0, 0, 0, 0, 0, 0};
    if (quad == 0) {
      float gs = (gt == 2) ? N2L2E : NL2E;
#pragma unroll
      for (int j = 0; j < 5; ++j) v[j] = (_Float16)(Wih1[(gt * 128 + col) * 5 + j] * gs);
    }
    bx[gt] = v;
  }
  f32x4 biasv[4];
#pragma unroll
  for (int gt = 0; gt < 4; ++gt) {
    float b = b1c[gt * 128 + col];
    biasv[gt][0] = b; biasv[gt][1] = b; biasv[gt][2] = b; biasv[gt][3] = b;
  }

  half8 xp = {0, 0, 0, 0, 0, 0, 0, 0};
  if (quad == 0) xp = *(const half8*)&xpad[((size_t)(wg * TS) * 16 + l15) * 8];

  float c[4] = {0, 0, 0, 0};
  float ssum = 0.0f, ssq = 0.0f;
  _Float16* hs1w = hs1 + (size_t)wg * TS * 2048;

  for (int t = 0; t < TS; ++t) {
    BAR();                               // h(t-1) (and t=0 zero-init) visible
    half8 ah[4];                         // issue LDS reads first...
#pragma unroll
    for (int kt = 0; kt < 4; ++kt)
      ah[kt] = *(const half8*)&hb[t & 1][kt * 512 + rbase];
    if (t > 0) {                         // coalesced h(t-1) -> hs1 (8 B/thread)
      float2 cp = *(const float2*)&hb[t & 1][tid * 4];
      *(float2*)&hs1w[(size_t)(t - 1) * 2048 + tid * 4] = cp;
    }
    f32x4 acc[4];                        // ...x-part MFMAs hide LDS latency
#pragma unroll
    for (int gt = 0; gt < 4; ++gt)
      acc[gt] = __builtin_amdgcn_mfma_f32_16x16x32_f16(xp, bx[gt], biasv[gt], 0, 0, 0);
    if (t + 1 < TS && quad == 0)
      xp = *(const half8*)&xpad[((size_t)(wg * TS + t + 1) * 16 + l15) * 8];
#pragma unroll
    for (int kt = 0; kt < 4; ++kt)
#pragma unroll
      for (int gt = 0; gt < 4; ++gt)
        acc[gt] = __builtin_amdgcn_mfma_f32_16x16x32_f16(ah[kt], bh[kt][gt], acc[gt], 0, 0, 0);
    const int wb = (t + 1) & 1;
    float hv4[4];
#pragma unroll
    for (int r = 0; r < 4; ++r) {
      float hv = lstm_cell(acc[0][r], acc[1][r], acc[2][r], acc[3][r], c[r]);
      hb[wb][wbase + r * 8] = (_Float16)hv;
      hv4[r] = hv;
    }
#pragma unroll
    for (int r = 0; r < 4; ++r) { ssum += hv4[r]; ssq += hv4[r] * hv4[r]; }
  }
  BAR();                                 // h(127) visible
  {
    float2 cp = *(const float2*)&hb[0][tid * 4];
    *(float2*)&hs1w[(size_t)(TS - 1) * 2048 + tid * 4] = cp;
  }
  float s = ssum, q = ssq;
  s += __shfl_xor(s, 16); s += __shfl_xor(s, 32);
  q += __shfl_xor(q, 16); q += __shfl_xor(q, 32);
  if (quad == 0) {
    atomicAdd(&s1sum[inp * HID + col], s);
    atomicAdd(&s1sq[inp * HID + col], q);
  }
}

// ---------------------------------------------------------------------------
// Mid: BN1-folded scaled W2 (fp16, B-frag order) + effective bias2.
// ---------------------------------------------------------------------------
__global__ void mid_kernel(const float* __restrict__ s1sum, const float* __restrict__ s1sq,
                           const float* __restrict__ g1, const float* __restrict__ b1,
                           const float* __restrict__ Wih2,
                           const float* __restrict__ bih2, const float* __restrict__ bhh2,
                           _Float16* __restrict__ w2s, float* __restrict__ bias2eff) {
  int bid = blockIdx.x, tid = threadIdx.x;
  __shared__ float scB[8];
  __shared__ float shL[128];
  if (bid < 96) {                        // w2s: [3][16 kq][512 g][8] B-frag
    int i = bid * 256 + tid;             // [0, 24576)
    int inp = i >> 13, i8 = i & 8191;    // kq uniform per block
    int kq = i8 >> 9, g = i8 & 511;
    int k0 = (kq >> 2) * 32 + (kq & 3) * 8;
    if (tid < 8) {
      int k = k0 + tid;
      float m = s1sum[inp * HID + k] * INV_N;
      float v = s1sq[inp * HID + k] * INV_N - m * m;
      scB[tid] = g1[k] * rsqrtf(v + 1e-5f);
    }
    __syncthreads();
    float gs = ((g >> 7) == 2) ? N2L2E : NL2E;
    const float* wr = Wih2 + (size_t)g * HID + k0;
    half8 v;
#pragma unroll
    for (int j = 0; j < 8; ++j) v[j] = (_Float16)(scB[j] * wr[j] * gs);
    *(half8*)&w2s[((size_t)inp * 8192 + i8) * 8] = v;
  } else {                               // bias2eff: [3][512], gate-scaled
    int i = (bid - 96) * 256 + tid;      // [0, 1536); inp uniform per block
    int inp = i >> 9, g = i & 511;
    if (tid < 128) {
      float m = s1sum[inp * HID + tid] * INV_N;
      float v = s1sq[inp * HID + tid] * INV_N - m * m;
      float s = g1[tid] * rsqrtf(v + 1e-5f);
      shL[tid] = b1[tid] - m * s;
    }
    __syncthreads();
    float acc = bih2[g] + bhh2[g];
    for (int h = 0; h < HID; ++h) acc += shL[h] * Wih2[(size_t)g * HID + h];
    float gs = ((g >> 7) == 2) ? N2L2E : NL2E;
    bias2eff[i] = acc * gs;
  }
}

// ---------------------------------------------------------------------------
// LSTM layer 2: fused (folded-BN1) input GEMM + recurrence. 96 WGs x 512.
// ---------------------------------------------------------------------------
__global__ __launch_bounds__(512, 2) void lstm2_kernel(
    const _Float16* __restrict__ hs1,    // [96][128][2048] A-frag order
    const _Float16* __restrict__ whhT2,  // [16 kq][512 g][8] B-frag, scaled
    const _Float16* __restrict__ w2s,    // [3][16 kq][512 g][8] B-frag, scaled
    const float* __restrict__ bias2eff,  // [3][512] scaled
    _Float16* __restrict__ h_last,       // [1536][128]
    float* __restrict__ s2sum, float* __restrict__ s2sq) {
  const int wg = blockIdx.x;             // tile 0..95
  const int inp = wg >> 5;
  const int gr0 = wg * 16;
  const int tid = threadIdx.x;
  const int w = tid >> 6;
  const int lane = tid & 63;
  const int l15 = lane & 15;
  const int quad = lane >> 4;
  const int col = w * 16 + l15;

  __shared__ _Float16 hb[2][2048];
  for (int i = tid; i < 4096; i += 512) ((_Float16*)hb)[i] = (_Float16)0.0f;

  const int rbase = (quad * 16 + l15) * 8;
  const int wbase = (w >> 1) * 512 + ((w & 1) * 2 + (l15 >> 3)) * 128 +
                    quad * 32 + (l15 & 7);

  const _Float16* w2sI = w2s + (size_t)inp * HID * NGATE;
  half8 bh[4][4], bxw[4][4];
#pragma unroll
  for (int kt = 0; kt < 4; ++kt)
#pragma unroll
    for (int gt = 0; gt < 4; ++gt) {
      size_t gi = (size_t)((kt * 4 + quad) * 512 + gt * 128 + col) * 8;
      bh[kt][gt] = *(const half8*)&whhT2[gi];
      bxw[kt][gt] = *(const half8*)&w2sI[gi];
    }
  f32x4 biasv[4];
#pragma unroll
  for (int gt = 0; gt < 4; ++gt) {
    float b = bias2eff[inp * NGATE + gt * 128 + col];
    biasv[gt][0] = b; biasv[gt][1] = b; biasv[gt][2] = b; biasv[gt][3] = b;
  }

  const _Float16* hg = hs1 + (size_t)wg * TS * 2048;
  half8 a2A[4], a2B[4];                  // 2-deep prefetch (coalesced 16B loads)
#pragma unroll
  for (int kt = 0; kt < 4; ++kt) {
    a2A[kt] = *(const half8*)&hg[kt * 512 + rbase];
    a2B[kt] = *(const half8*)&hg[(size_t)2048 + kt * 512 + rbase];
  }

  float c[4] = {0, 0, 0, 0};
  float ssum = 0.0f, ssq = 0.0f;

  auto step = [&](int t, half8 (&cur)[4]) {
    BAR();                               // h(t-1) visible; vmcnt untouched
    half8 ah[4];                         // issue LDS reads first...
#pragma unroll
    for (int kt = 0; kt < 4; ++kt)
      ah[kt] = *(const half8*)&hb[t & 1][kt * 512 + rbase];
    f32x4 acc[4];                        // ...x-part MFMAs hide LDS latency
#pragma unroll
    for (int gt = 0; gt < 4; ++gt)
      acc[gt] = __builtin_amdgcn_mfma_f32_16x16x32_f16(cur[0], bxw[0][gt], biasv[gt], 0, 0, 0);
#pragma unroll
    for (int kt = 1; kt < 4; ++kt)
#pragma unroll
      for (int gt = 0; gt < 4; ++gt)
        acc[gt] = __builtin_amdgcn_mfma_f32_16x16x32_f16(cur[kt], bxw[kt][gt], acc[gt], 0, 0, 0);
    if (t + 2 < TS) {                    // prefetch t+2 into regs just consumed
#pragma unroll
      for (int kt = 0; kt < 4; ++kt)
        cur[kt] = *(const half8*)&hg[(size_t)(t + 2) * 2048 + kt * 512 + rbase];
    }
#pragma unroll
    for (int kt = 0; kt < 4; ++kt)
#pragma unroll
      for (int gt = 0; gt < 4; ++gt)
        acc[gt] = __builtin_amdgcn_mfma_f32_16x16x32_f16(ah[kt], bh[kt][gt], acc[gt], 0, 0, 0);
    const int wb = (t + 1) & 1;
    float hv4[4];
#pragma unroll
    for (int r = 0; r < 4; ++r) {
      float hv = lstm_cell(acc[0][r], acc[1][r], acc[2][r], acc[3][r], c[r]);
      hb[wb][wbase + r * 8] = (_Float16)hv;
      hv4[r] = hv;
    }
#pragma unroll
    for (int r = 0; r < 4; ++r) { ssum += hv4[r]; ssq += hv4[r] * hv4[r]; }
  };

  for (int t = 0; t < TS; t += 2) {
    step(t, a2A);
    step(t + 1, a2B);
  }

  BAR();                                 // h(127) visible in hb[0]
#pragma unroll
  for (int r = 0; r < 4; ++r)
    h_last[(size_t)(gr0 + quad * 4 + r) * HID + col] = hb[0][wbase + r * 8];

  float s = ssum, q = ssq;
  s += __shfl_xor(s, 16); s += __shfl_xor(s, 32);
  q += __shfl_xor(q, 16); q += __shfl_xor(q, 32);
  if (quad == 0) {
    atomicAdd(&s2sum[inp * HID + col], s);
    atomicAdd(&s2sq[inp * HID + col], q);
  }
}

// ---------------------------------------------------------------------------
// Head: BN2 finalize + FC + L2 normalize. 96 WGs x 16 rows.
// ---------------------------------------------------------------------------
__global__ __launch_bounds__(256, 1) void head_kernel(
    const _Float16* __restrict__ h_last,
    const float* __restrict__ s2sum, const float* __restrict__ s2sq,
    const float* __restrict__ g2, const float* __restrict__ b2,
    const float* __restrict__ fcW, const float* __restrict__ fcb,
    float* __restrict__ out) {
  const int wg = blockIdx.x;
  const int inp = wg >> 5;
  const int gr0 = wg * 16;
  const int tid = threadIdx.x;

  __shared__ float fcwT[128][132];       // fcwT[h][j] = fcW[j][h]
  __shared__ float bnh[16][132];
  __shared__ float s2[128], sh2[128];
  __shared__ float part[16][16];
  __shared__ float inv[16];

  if (tid < 128) {
    float m = s2sum[inp * HID + tid] * INV_N;
    float v = s2sq[inp * HID + tid] * INV_N - m * m;
    float s = g2[tid] * rsqrtf(v + 1e-5f);
    s2[tid] = s; sh2[tid] = b2[tid] - m * s;
  }
  for (int i = tid; i < 16384; i += 256) {
    int j = i >> 7, h = i & 127;
    fcwT[h][j] = fcW[i];
  }
  __syncthreads();
  {
    int row = tid >> 4, c0 = (tid & 15) * 8;
#pragma unroll
    for (int k = 0; k < 8; ++k) {
      int h = c0 + k;
      bnh[row][h] = (float)h_last[(gr0 + row) * HID + h] * s2[h] + sh2[h];
    }
  }
  __syncthreads();
  const int row = tid >> 4, jl = tid & 15;
  float emb[8];
  float sq = 0.0f;
#pragma unroll
  for (int jj = 0; jj < 8; ++jj) {
    int j = jl + jj * 16;
    float acc = fcb[j];
    for (int h = 0; h < HID; ++h) acc += bnh[row][h] * fcwT[h][j];
    emb[jj] = acc; sq += acc * acc;
  }
  part[row][jl] = sq;
  __syncthreads();
  if (tid < 16) {
    float s = 0.0f;
    for (int k = 0; k < 16; ++k) s += part[tid][k];
    float nrm = sqrtf(s);
    inv[tid] = 1.0f / fmaxf(nrm, 1e-12f);
  }
  __syncthreads();
#pragma unroll
  for (int jj = 0; jj < 8; ++jj)
    out[(gr0 + row) * HID + jl + jj * 16] = emb[jj] * inv[row];
}

// ---------------------------------------------------------------------------
extern "C" void kernel_launch(void* const* d_in, const int* in_sizes, int n_in,
                              void* d_out, int out_size, void* d_ws, size_t ws_size,
                              hipStream_t stream) {
  const float* a    = (const float*)d_in[0];
  const float* p    = (const float*)d_in[1];
  const float* nn   = (const float*)d_in[2];
  const float* Wih1 = (const float*)d_in[3];
  const float* Whh1 = (const float*)d_in[4];
  const float* bih1 = (const float*)d_in[5];
  const float* bhh1 = (const float*)d_in[6];
  const float* g1   = (const float*)d_in[7];
  const float* b1   = (const float*)d_in[8];
  const float* Wih2 = (const float*)d_in[9];
  const float* Whh2 = (const float*)d_in[10];
  const float* bih2 = (const float*)d_in[11];
  const float* bhh2 = (const float*)d_in[12];
  const float* g2   = (const float*)d_in[13];
  const float* b2   = (const float*)d_in[14];
  const float* fcW  = (const float*)d_in[15];
  const float* fcb  = (const float*)d_in[16];

  char* ws = (char*)d_ws;
  float* s1sum = (float*)(ws + 0);            // 384 f32
  float* s1sq  = s1sum + 384;
  float* s2sum = s1sum + 768;
  float* s2sq  = s1sum + 1152;                // stats end @6144B
  float* b1c      = (float*)(ws + 6144);      // 512 f32 -> @8192
  float* bias2eff = (float*)(ws + 8192);      // 1536 f32 -> @14336
  _Float16* whhT1 = (_Float16*)(ws + 14336);    // 131072B -> @145408
  _Float16* whhT2 = (_Float16*)(ws + 145408);   // 131072B -> @276480
  _Float16* w2s   = (_Float16*)(ws + 276480);   // 393216B -> @669696
  _Float16* hlast = (_Float16*)(ws + 669696);   // 393216B -> @1062912
  _Float16* xpad  = (_Float16*)(ws + 1062912);  // 3145728B -> @4208640
  _Float16* hs1   = (_Float16*)(ws + 4208640);  // 50331648B -> ~54.5MB total

  hipMemsetAsync(ws, 0, 6144, stream);  // zero BN stats accumulators

  prep_all<<<834, 256, 0, stream>>>(a, p, nn, Whh1, Whh2, bih1, bhh1,
                                    xpad, whhT1, whhT2, b1c);
  lstm1_kernel<<<96, 512, 0, stream>>>(xpad, Wih1, b1c, whhT1, hs1, s1sum, s1sq);
  mid_kernel<<<102, 256, 0, stream>>>(s1sum, s1sq, g1, b1, Wih2, bih2, bhh2,
                                      w2s, bias2eff);
  lstm2_kernel<<<96, 512, 0, stream>>>(hs1, whhT2, w2s, bias2eff, hlast, s2sum, s2sq);
  head_kernel<<<96, 256, 0, stream>>>(hlast, s2sum, s2sq, g2, b2, fcW, fcb, (float*)d_out);
}